// Round 2
// baseline (6297.693 us; speedup 1.0000x reference)
//
#include <hip/hip_runtime.h>

// CustomLSTMClassifier on MI355X (gfx950)
// Design: persistent 128-block kernel, 512 sequential LSTM steps.
//  - fp16 weights/activations, fp32 accum + fp32 cell state in registers.
//  - Block owns 8 hidden units (32 gate cols f/i/o/g). Weight panel prepacked
//    in MFMA-fragment order, staged to LDS once (96 KB), reused 512 steps.
//  - h exchanged via double-buffered global fp16 buffer with AGENT-scope
//    relaxed atomics (sc1) + per-step counter barrier ctr[t].
//  - x-GEMM for step t+1 overlaps the barrier wait for step t.

typedef _Float16 f16;
typedef _Float16 f16x8 __attribute__((ext_vector_type(8)));
typedef float f32x4 __attribute__((ext_vector_type(4)));
typedef unsigned short u16;
typedef unsigned int u32;
typedef unsigned long long u64;

#define NBLK 128
#define SEQ 512

// workspace layout (bytes)
#define XH_OFF 0ull
#define XH_BYTES (64ull * 512 * 512 * 2)      // 33554432  x in fp16, [t][b][k]
#define WPRE_OFF (XH_OFF + XH_BYTES)
#define WPRE_BYTES (128ull * 48 * 2 * 64 * 16) // 12582912  per-block fragment-packed W
#define BIAS_OFF (WPRE_OFF + WPRE_BYTES)
#define BIAS_BYTES (128ull * 32 * 4)
#define HBUF_OFF (BIAS_OFF + BIAS_BYTES)
#define HBUF_BYTES (2ull * 64 * 1024 * 2)      // double-buffered h (fp16)
#define HFIN_OFF (HBUF_OFF + HBUF_BYTES)
#define HFIN_BYTES (64ull * 1024 * 4)          // final h (fp32)
#define CTR_OFF (HFIN_OFF + HFIN_BYTES)
#define CTR_BYTES (512ull * 4)
#define WS_NEEDED (CTR_OFF + CTR_BYTES)

// ---------------------------------------------------------------------------
// prep: convert x to fp16 [t][b][k]; prepack weights into per-block MFMA
// fragment order; pack bias; zero ctr[] and h buffer 0.
// W_pre frag index = ((bl*48 + kt)*2 + nt)*64 + lane ; elem e (k-fastest).
//   col c = nt*16 + (lane&15)  (c<8:f, <16:i, <24:o, <32:g), unit = c&7
//   k    = kt*32 + 8*(lane>>4) + e   (k<512 = x part, else h part)
// ---------------------------------------------------------------------------
__global__ void prep_kernel(const float* __restrict__ xin,
                            const float* __restrict__ wf, const float* __restrict__ wi,
                            const float* __restrict__ wo, const float* __restrict__ wc,
                            const float* __restrict__ bfp, const float* __restrict__ bip,
                            const float* __restrict__ bop, const float* __restrict__ bcp,
                            f16* __restrict__ x_h, f16x8* __restrict__ W_pre,
                            float* __restrict__ bias_pre, u32* __restrict__ ctr,
                            u32* __restrict__ hzero) {
  long long id = (long long)blockIdx.x * 256 + threadIdx.x;
  const long long NX = 16777216;  // 64*512*512
  const long long NW = 786432;    // 128*48*2*64 fragments
  const long long NB_ = 4096;     // 128*32 bias
  const long long NC = 512;       // counters
  const long long NH = 32768;     // h buffer 0 as u32 words
  if (id < NX) {
    int b = (int)(id >> 18);
    int t = (int)((id >> 9) & 511);
    int k = (int)(id & 511);
    x_h[(((long long)t * 64 + b) << 9) | k] = (f16)xin[id];
  } else if ((id -= NX) < NW) {
    int lane = (int)(id & 63);
    int nt = (int)((id >> 6) & 1);
    int ktbl = (int)(id >> 7);
    int kt = ktbl % 48;
    int bl = ktbl / 48;
    int c = nt * 16 + (lane & 15);
    int g = c >> 3;
    int j = bl * 8 + (c & 7);
    int kbase = kt * 32 + 8 * (lane >> 4);
    const float* src = (g == 0) ? wf : (g == 1) ? wi : (g == 2) ? wo : wc;
    const float* row = src + (long long)j * 1536 + kbase;
    f16x8 v;
#pragma unroll
    for (int e = 0; e < 8; ++e) v[e] = (f16)row[e];
    W_pre[id] = v;
  } else if ((id -= NW) < NB_) {
    int bl = (int)(id >> 5);
    int c = (int)(id & 31);
    int g = c >> 3;
    int j = bl * 8 + (c & 7);
    const float* src = (g == 0) ? bfp : (g == 1) ? bip : (g == 2) ? bop : bcp;
    bias_pre[id] = src[j];
  } else if ((id -= NB_) < NC) {
    ctr[id] = 0u;
  } else if ((id -= NC) < NH) {
    hzero[id] = 0u;
  }
}

// ---------------------------------------------------------------------------
__device__ __forceinline__ f16x8 ld_h_frag(const u16* p) {
  u64 a0 = __hip_atomic_load((u64*)p, __ATOMIC_RELAXED, __HIP_MEMORY_SCOPE_AGENT);
  u64 a1 = __hip_atomic_load(((u64*)p) + 1, __ATOMIC_RELAXED, __HIP_MEMORY_SCOPE_AGENT);
  union { u64 u2[2]; f16x8 v; } cv;
  cv.u2[0] = a0; cv.u2[1] = a1;
  return cv.v;
}

__device__ __forceinline__ float sgm(float x) { return 1.0f / (1.0f + __expf(-x)); }
__device__ __forceinline__ float tnh(float x) { return 1.0f - 2.0f / (__expf(2.0f * x) + 1.0f); }

__global__ __launch_bounds__(256, 1) void lstm_kernel(const f16* __restrict__ x_h,
                                                      const f16x8* __restrict__ W_pre,
                                                      const float* __restrict__ bias_pre,
                                                      u16* hbuf, float* hfinal, u32* ctr) {
  __shared__ f16x8 Wlds[48 * 2 * 64];  // 96 KB
  const int tid = threadIdx.x;
  const int bl = blockIdx.x;
  const int lane = tid & 63;
  const int wv = tid >> 6;  // 4 waves = 4 M-tiles of 16 batch rows

  {  // stage weight panel once
    const f16x8* src = W_pre + (long long)bl * (48 * 2 * 64);
    for (int i = tid; i < 48 * 2 * 64; i += 256) Wlds[i] = src[i];
  }
  __syncthreads();

  const int l15 = lane & 15;
  const int lq = lane >> 4;
  const int arow = 16 * wv + l15;           // A-fragment batch row
  const float bias0 = bias_pre[bl * 32 + l15];
  const float bias1 = bias_pre[bl * 32 + 16 + l15];
  const int jcol = bl * 8 + (lane & 7);     // owned hidden unit column
  const bool act = (l15 < 8);
  float cst0 = 0.f, cst1 = 0.f, cst2 = 0.f, cst3 = 0.f;  // fp32 cell state

  f32x4 xacc[2][2];  // [ntile][chain], x-part partial gates for next step

  auto xgemm = [&](int T) {
    f32x4 z = {0.f, 0.f, 0.f, 0.f};
    xacc[0][0] = z; xacc[0][1] = z; xacc[1][0] = z; xacc[1][1] = z;
    const f16* xr = x_h + (((long long)T * 64 + arow) << 9) + 8 * lq;
    f16x8 xf[16];
#pragma unroll
    for (int kk = 0; kk < 16; ++kk) xf[kk] = *(const f16x8*)(xr + kk * 32);
#pragma unroll
    for (int kk = 0; kk < 16; ++kk) {
      f16x8 b0 = Wlds[(kk * 2 + 0) * 64 + lane];
      f16x8 b1 = Wlds[(kk * 2 + 1) * 64 + lane];
      xacc[0][kk & 1] = __builtin_amdgcn_mfma_f32_16x16x32_f16(xf[kk], b0, xacc[0][kk & 1], 0, 0, 0);
      xacc[1][kk & 1] = __builtin_amdgcn_mfma_f32_16x16x32_f16(xf[kk], b1, xacc[1][kk & 1], 0, 0, 0);
    }
  };

  xgemm(0);  // prologue: x contribution for t=0

  for (int t = 0; t < SEQ; ++t) {
    const u16* hr = hbuf + (size_t)(t & 1) * 65536;
    u16* hw = hbuf + (size_t)((t + 1) & 1) * 65536;

    f32x4 acc00 = xacc[0][0], acc01 = xacc[0][1];
    f32x4 acc10 = xacc[1][0], acc11 = xacc[1][1];

    // ---- h-GEMM: K=1024, 32 k-tiles; issue all fragment loads up front ----
    const u16* hrow = hr + arow * 1024 + 8 * lq;
    f16x8 hfr[32];
#pragma unroll
    for (int kt = 0; kt < 32; ++kt) hfr[kt] = ld_h_frag(hrow + kt * 32);
#pragma unroll
    for (int kt = 0; kt < 32; ++kt) {
      f16x8 b0 = Wlds[((16 + kt) * 2 + 0) * 64 + lane];
      f16x8 b1 = Wlds[((16 + kt) * 2 + 1) * 64 + lane];
      if (kt & 1) {
        acc01 = __builtin_amdgcn_mfma_f32_16x16x32_f16(hfr[kt], b0, acc01, 0, 0, 0);
        acc11 = __builtin_amdgcn_mfma_f32_16x16x32_f16(hfr[kt], b1, acc11, 0, 0, 0);
      } else {
        acc00 = __builtin_amdgcn_mfma_f32_16x16x32_f16(hfr[kt], b0, acc00, 0, 0, 0);
        acc10 = __builtin_amdgcn_mfma_f32_16x16x32_f16(hfr[kt], b1, acc10, 0, 0, 0);
      }
    }

    // ---- gates -> elementwise.  D layout: col=lane&15, row=(lane>>4)*4+r ----
    f32x4 g0 = acc00 + acc01;  // cols 0..15: f(0-7), i(8-15)
    f32x4 g1 = acc10 + acc11;  // cols 16..31: o(0-7), g(8-15)
#pragma unroll
    for (int r = 0; r < 4; ++r) { g0[r] += bias0; g1[r] += bias1; }

    float iv0 = __shfl_xor(g0[0], 8), iv1 = __shfl_xor(g0[1], 8);
    float iv2 = __shfl_xor(g0[2], 8), iv3 = __shfl_xor(g0[3], 8);
    float gv0 = __shfl_xor(g1[0], 8), gv1 = __shfl_xor(g1[1], 8);
    float gv2 = __shfl_xor(g1[2], 8), gv3 = __shfl_xor(g1[3], 8);

    if (act) {
      const int brb = 16 * wv + 4 * lq;
#pragma unroll
      for (int r = 0; r < 4; ++r) {
        float fpre = (r == 0) ? g0[0] : (r == 1) ? g0[1] : (r == 2) ? g0[2] : g0[3];
        float opre = (r == 0) ? g1[0] : (r == 1) ? g1[1] : (r == 2) ? g1[2] : g1[3];
        float ipre = (r == 0) ? iv0 : (r == 1) ? iv1 : (r == 2) ? iv2 : iv3;
        float gpre = (r == 0) ? gv0 : (r == 1) ? gv1 : (r == 2) ? gv2 : gv3;
        float cold = (r == 0) ? cst0 : (r == 1) ? cst1 : (r == 2) ? cst2 : cst3;
        float cn = sgm(fpre) * cold + sgm(ipre) * tnh(gpre);
        float hv = sgm(opre) * tnh(cn);
        if (r == 0) cst0 = cn; else if (r == 1) cst1 = cn; else if (r == 2) cst2 = cn; else cst3 = cn;
        union { f16 h; u16 u; } cv2; cv2.h = (f16)hv;
        __hip_atomic_store(&hw[(brb + r) * 1024 + jcol], cv2.u, __ATOMIC_RELAXED,
                           __HIP_MEMORY_SCOPE_AGENT);
        if (t == SEQ - 1) hfinal[(brb + r) * 1024 + jcol] = hv;
      }
    }

    // ---- publish + barrier; overlap x-GEMM(t+1) with the wait ----
    asm volatile("s_waitcnt vmcnt(0)" ::: "memory");
    __syncthreads();
    if (tid == 0)
      __hip_atomic_fetch_add(&ctr[t], 1u, __ATOMIC_RELAXED, __HIP_MEMORY_SCOPE_AGENT);
    if (t + 1 < SEQ) xgemm(t + 1);
    if (tid == 0) {
      u32 it = 0;
      while (__hip_atomic_load(&ctr[t], __ATOMIC_RELAXED, __HIP_MEMORY_SCOPE_AGENT) < NBLK) {
        __builtin_amdgcn_s_sleep(2);
        if (++it > 600000u) break;  // bail: wrong answer beats a hang
      }
    }
    __syncthreads();
  }
}

// ---------------------------------------------------------------------------
__global__ void logits_kernel(const float* __restrict__ hfinal, const float* __restrict__ ow,
                              const float* __restrict__ ob, float* __restrict__ out) {
  int b = blockIdx.x / 10;
  int o = blockIdx.x % 10;
  int lane = threadIdx.x;
  const float* hrow = hfinal + b * 1024;
  const float* wrow = ow + o * 1024;
  float s = 0.f;
#pragma unroll 4
  for (int i = lane; i < 1024; i += 64) s += hrow[i] * wrow[i];
#pragma unroll
  for (int off = 32; off; off >>= 1) s += __shfl_xor(s, off);
  if (lane == 0) out[b * 10 + o] = s + ob[o];
}

// ---------------------------------------------------------------------------
extern "C" void kernel_launch(void* const* d_in, const int* in_sizes, int n_in,
                              void* d_out, int out_size, void* d_ws, size_t ws_size,
                              hipStream_t stream) {
  const float* xin = (const float*)d_in[0];
  const float* wf = (const float*)d_in[1];
  const float* bf = (const float*)d_in[2];
  const float* wi = (const float*)d_in[3];
  const float* bi = (const float*)d_in[4];
  const float* wo = (const float*)d_in[5];
  const float* bo = (const float*)d_in[6];
  const float* wc = (const float*)d_in[7];
  const float* bc = (const float*)d_in[8];
  const float* ow = (const float*)d_in[9];
  const float* ob = (const float*)d_in[10];
  (void)in_sizes; (void)n_in; (void)out_size;

  if (ws_size < WS_NEEDED) return;  // need ~46.7 MB scratch
  char* ws = (char*)d_ws;
  f16* x_h = (f16*)(ws + XH_OFF);
  f16x8* W_pre = (f16x8*)(ws + WPRE_OFF);
  float* bias_pre = (float*)(ws + BIAS_OFF);
  u16* hbuf = (u16*)(ws + HBUF_OFF);
  float* hfinal = (float*)(ws + HFIN_OFF);
  u32* ctr = (u32*)(ws + CTR_OFF);

  const long long total = 16777216LL + 786432 + 4096 + 512 + 32768;
  const int pblocks = (int)((total + 255) / 256);
  prep_kernel<<<pblocks, 256, 0, stream>>>(xin, wf, wi, wo, wc, bf, bi, bo, bc, x_h, W_pre,
                                           bias_pre, ctr, (u32*)hbuf);
  lstm_kernel<<<NBLK, 256, 0, stream>>>(x_h, W_pre, bias_pre, hbuf, hfinal, ctr);
  logits_kernel<<<640, 64, 0, stream>>>(hfinal, ow, ob, (float*)d_out);
}

// Round 3
// 4830.882 us; speedup vs baseline: 1.3036x; 1.3036x over previous
//
#include <hip/hip_runtime.h>

// CustomLSTMClassifier on MI355X (gfx950) — round 3
// Persistent 128-block kernel, 512 sequential LSTM steps.
//  - fp16 weights/activations, fp32 accum + fp32 cell state in registers.
//  - Block owns 8 hidden units (32 gate cols f/i/o/g). Weight panel prepacked
//    in MFMA-fragment order, staged to LDS once (96 KB), reused 512 steps.
//  - h exchanged via double-buffered global buffer in MFMA-FRAGMENT ORDER:
//    writers scatter 2B agent atomic stores (write-through to L3); readers do
//    agent acquire fence (buffer_inv) + plain coalesced dwordx4 loads.
//  - barrier: per-block flag words flag[t][bl] (no same-address RMW storm);
//    wave0 polls 128 flags with 2 coalesced sc1 loads/lane + ballot.
//  - x-GEMM for step t+1 overlaps the barrier wait for step t.

typedef _Float16 f16;
typedef _Float16 f16x8 __attribute__((ext_vector_type(8)));
typedef float f32x4 __attribute__((ext_vector_type(4)));
typedef unsigned short u16;
typedef unsigned int u32;
typedef unsigned long long u64;

#define NBLK 128
#define SEQ 512

// workspace layout (bytes)
#define XH_OFF 0ull
#define XH_BYTES (64ull * 512 * 512 * 2)       // 33554432  x in fp16, [t][b][k]
#define WPRE_OFF (XH_OFF + XH_BYTES)
#define WPRE_BYTES (128ull * 48 * 2 * 64 * 16) // 12582912  per-block fragment-packed W
#define BIAS_OFF (WPRE_OFF + WPRE_BYTES)
#define BIAS_BYTES (128ull * 32 * 4)
#define HBUF_OFF (BIAS_OFF + BIAS_BYTES)
#define HBUF_BYTES (2ull * 32 * 64 * 4 * 16)   // 262144: dbuf h, frag order [kt][row][lq]x f16x8
#define HFIN_OFF (HBUF_OFF + HBUF_BYTES)
#define HFIN_BYTES (64ull * 1024 * 4)          // final h (fp32)
#define FLG_OFF (HFIN_OFF + HFIN_BYTES)
#define FLG_BYTES (512ull * 128 * 4)           // 262144: flag[t][bl]
#define WS_NEEDED (FLG_OFF + FLG_BYTES)

// ---------------------------------------------------------------------------
// prep: convert x to fp16 [t][b][k]; prepack weights into per-block MFMA
// fragment order; pack bias; zero flags and h fragment-buffer 0.
// W_pre frag index = ((bl*48 + kt)*2 + nt)*64 + lane ; elem e (k-fastest).
//   col c = nt*16 + (lane&15)  (c<8:f, <16:i, <24:o, <32:g), unit = c&7
//   k    = kt*32 + 8*(lane>>4) + e   (k<512 = x part, else h part)
// ---------------------------------------------------------------------------
__global__ void prep_kernel(const float* __restrict__ xin,
                            const float* __restrict__ wf, const float* __restrict__ wi,
                            const float* __restrict__ wo, const float* __restrict__ wc,
                            const float* __restrict__ bfp, const float* __restrict__ bip,
                            const float* __restrict__ bop, const float* __restrict__ bcp,
                            f16* __restrict__ x_h, f16x8* __restrict__ W_pre,
                            float* __restrict__ bias_pre, u32* __restrict__ flagz,
                            u32* __restrict__ hzero) {
  long long id = (long long)blockIdx.x * 256 + threadIdx.x;
  const long long NX = 16777216;  // 64*512*512
  const long long NW = 786432;    // 128*48*2*64 fragments
  const long long NB_ = 4096;     // 128*32 bias
  const long long NF = 65536;     // 512*128 flags
  const long long NH = 32768;     // h frag buffer 0 as u32 words (128 KB)
  if (id < NX) {
    int b = (int)(id >> 18);
    int t = (int)((id >> 9) & 511);
    int k = (int)(id & 511);
    x_h[(((long long)t * 64 + b) << 9) | k] = (f16)xin[id];
  } else if ((id -= NX) < NW) {
    int lane = (int)(id & 63);
    int nt = (int)((id >> 6) & 1);
    int ktbl = (int)(id >> 7);
    int kt = ktbl % 48;
    int bl = ktbl / 48;
    int c = nt * 16 + (lane & 15);
    int g = c >> 3;
    int j = bl * 8 + (c & 7);
    int kbase = kt * 32 + 8 * (lane >> 4);
    const float* src = (g == 0) ? wf : (g == 1) ? wi : (g == 2) ? wo : wc;
    const float* row = src + (long long)j * 1536 + kbase;
    f16x8 v;
#pragma unroll
    for (int e = 0; e < 8; ++e) v[e] = (f16)row[e];
    W_pre[id] = v;
  } else if ((id -= NW) < NB_) {
    int bl = (int)(id >> 5);
    int c = (int)(id & 31);
    int g = c >> 3;
    int j = bl * 8 + (c & 7);
    const float* src = (g == 0) ? bfp : (g == 1) ? bip : (g == 2) ? bop : bcp;
    bias_pre[id] = src[j];
  } else if ((id -= NB_) < NF) {
    flagz[id] = 0u;
  } else if ((id -= NF) < NH) {
    hzero[id] = 0u;
  }
}

// ---------------------------------------------------------------------------
__device__ __forceinline__ float sgm(float x) { return 1.0f / (1.0f + __expf(-x)); }
__device__ __forceinline__ float tnh(float x) { return 1.0f - 2.0f / (__expf(2.0f * x) + 1.0f); }

// h fragment buffer layout (per 128 KB buffer):
//   f16x8 unit index = kt*256 + row*4 + lq   (kt<32, row<64, lq<4)
//   holds h[row][k] for k = kt*32 + lq*8 .. +8
__global__ __launch_bounds__(256, 1) void lstm_kernel(const f16* __restrict__ x_h,
                                                      const f16x8* __restrict__ W_pre,
                                                      const float* __restrict__ bias_pre,
                                                      f16x8* hfrag, float* hfinal, u32* flag) {
  __shared__ f16x8 Wlds[48 * 2 * 64];  // 96 KB
  const int tid = threadIdx.x;
  const int bl = blockIdx.x;
  const int lane = tid & 63;
  const int wv = tid >> 6;  // 4 waves = 4 M-tiles of 16 batch rows

  {  // stage weight panel once
    const f16x8* src = W_pre + (long long)bl * (48 * 2 * 64);
    for (int i = tid; i < 48 * 2 * 64; i += 256) Wlds[i] = src[i];
  }
  __syncthreads();

  const int l15 = lane & 15;
  const int lq = lane >> 4;
  const int arow = 16 * wv + l15;           // A-fragment batch row
  const float bias0 = bias_pre[bl * 32 + l15];
  const float bias1 = bias_pre[bl * 32 + 16 + l15];
  const int jcol = bl * 8 + (lane & 7);     // owned hidden unit column
  const bool act = (l15 < 8);
  // writer address pieces (fragment layout): kt=bl>>2 const, lq-slot=bl&3 const
  const int wkt = bl >> 2;
  const int wlq = bl & 3;
  float cst0 = 0.f, cst1 = 0.f, cst2 = 0.f, cst3 = 0.f;  // fp32 cell state

  f32x4 xacc[2][2];  // [ntile][chain], x-part partial gates for next step

  auto xgemm = [&](int T) {
    f32x4 z = {0.f, 0.f, 0.f, 0.f};
    xacc[0][0] = z; xacc[0][1] = z; xacc[1][0] = z; xacc[1][1] = z;
    const f16* xr = x_h + (((long long)T * 64 + arow) << 9) + 8 * lq;
    f16x8 xf[16];
#pragma unroll
    for (int kk = 0; kk < 16; ++kk) xf[kk] = *(const f16x8*)(xr + kk * 32);
#pragma unroll
    for (int kk = 0; kk < 16; ++kk) {
      f16x8 b0 = Wlds[(kk * 2 + 0) * 64 + lane];
      f16x8 b1 = Wlds[(kk * 2 + 1) * 64 + lane];
      xacc[0][kk & 1] = __builtin_amdgcn_mfma_f32_16x16x32_f16(xf[kk], b0, xacc[0][kk & 1], 0, 0, 0);
      xacc[1][kk & 1] = __builtin_amdgcn_mfma_f32_16x16x32_f16(xf[kk], b1, xacc[1][kk & 1], 0, 0, 0);
    }
  };

  xgemm(0);  // prologue: x contribution for t=0

  for (int t = 0; t < SEQ; ++t) {
    const f16x8* hb = hfrag + (size_t)(t & 1) * 8192;          // read buffer
    u16* hw = (u16*)hfrag + (size_t)((t + 1) & 1) * 65536;     // write buffer (u16 view)

    // make remote h stores (from step t-1) visible: invalidate L1/L2, then
    // plain coalesced loads (L2-cacheable, shared by 16 blocks/XCD)
    __builtin_amdgcn_fence(__ATOMIC_ACQUIRE, "agent");

    f32x4 acc00 = xacc[0][0], acc01 = xacc[0][1];
    f32x4 acc10 = xacc[1][0], acc11 = xacc[1][1];

    // ---- h-GEMM: K=1024, 32 k-tiles; fragment-order coalesced loads ----
    f16x8 hfr[32];
#pragma unroll
    for (int kt = 0; kt < 32; ++kt) hfr[kt] = hb[kt * 256 + arow * 4 + lq];
#pragma unroll
    for (int kt = 0; kt < 32; ++kt) {
      f16x8 b0 = Wlds[((16 + kt) * 2 + 0) * 64 + lane];
      f16x8 b1 = Wlds[((16 + kt) * 2 + 1) * 64 + lane];
      if (kt & 1) {
        acc01 = __builtin_amdgcn_mfma_f32_16x16x32_f16(hfr[kt], b0, acc01, 0, 0, 0);
        acc11 = __builtin_amdgcn_mfma_f32_16x16x32_f16(hfr[kt], b1, acc11, 0, 0, 0);
      } else {
        acc00 = __builtin_amdgcn_mfma_f32_16x16x32_f16(hfr[kt], b0, acc00, 0, 0, 0);
        acc10 = __builtin_amdgcn_mfma_f32_16x16x32_f16(hfr[kt], b1, acc10, 0, 0, 0);
      }
    }

    // ---- gates -> elementwise.  D layout: col=lane&15, row=(lane>>4)*4+r ----
    f32x4 g0 = acc00 + acc01;  // cols 0..15: f(0-7), i(8-15)
    f32x4 g1 = acc10 + acc11;  // cols 16..31: o(0-7), g(8-15)
#pragma unroll
    for (int r = 0; r < 4; ++r) { g0[r] += bias0; g1[r] += bias1; }

    float iv0 = __shfl_xor(g0[0], 8), iv1 = __shfl_xor(g0[1], 8);
    float iv2 = __shfl_xor(g0[2], 8), iv3 = __shfl_xor(g0[3], 8);
    float gv0 = __shfl_xor(g1[0], 8), gv1 = __shfl_xor(g1[1], 8);
    float gv2 = __shfl_xor(g1[2], 8), gv3 = __shfl_xor(g1[3], 8);

    if (act) {
      const int brb = 16 * wv + 4 * lq;
#pragma unroll
      for (int r = 0; r < 4; ++r) {
        float fpre = (r == 0) ? g0[0] : (r == 1) ? g0[1] : (r == 2) ? g0[2] : g0[3];
        float opre = (r == 0) ? g1[0] : (r == 1) ? g1[1] : (r == 2) ? g1[2] : g1[3];
        float ipre = (r == 0) ? iv0 : (r == 1) ? iv1 : (r == 2) ? iv2 : iv3;
        float gpre = (r == 0) ? gv0 : (r == 1) ? gv1 : (r == 2) ? gv2 : gv3;
        float cold = (r == 0) ? cst0 : (r == 1) ? cst1 : (r == 2) ? cst2 : cst3;
        float cn = sgm(fpre) * cold + sgm(ipre) * tnh(gpre);
        float hv = sgm(opre) * tnh(cn);
        if (r == 0) cst0 = cn; else if (r == 1) cst1 = cn; else if (r == 2) cst2 = cn; else cst3 = cn;
        union { f16 h; u16 u; } cv2; cv2.h = (f16)hv;
        int row = brb + r;
        // fragment-order write: u16 idx = wkt*2048 + row*32 + wlq*8 + l15
        __hip_atomic_store(&hw[wkt * 2048 + row * 32 + wlq * 8 + l15], cv2.u,
                           __ATOMIC_RELAXED, __HIP_MEMORY_SCOPE_AGENT);
        if (t == SEQ - 1) hfinal[row * 1024 + jcol] = hv;
      }
    }

    // ---- publish + flag barrier; overlap x-GEMM(t+1) with the wait ----
    __syncthreads();  // drains all waves' vmcnt: h stores at L3 before flag
    if (t + 1 < SEQ) {
      if (tid == 0)
        __hip_atomic_store(&flag[(size_t)t * NBLK + bl], 1u, __ATOMIC_RELAXED,
                           __HIP_MEMORY_SCOPE_AGENT);
      xgemm(t + 1);
      if (wv == 0) {
        const u32* fl = flag + (size_t)t * NBLK;
        u32 it = 0;
        while (true) {
          u32 a = __hip_atomic_load(fl + 2 * lane, __ATOMIC_RELAXED, __HIP_MEMORY_SCOPE_AGENT);
          u32 b = __hip_atomic_load(fl + 2 * lane + 1, __ATOMIC_RELAXED, __HIP_MEMORY_SCOPE_AGENT);
          if (__all((a & b) == 1u)) break;  // all 128 flags set
          __builtin_amdgcn_s_sleep(1);
          if (++it > 50000u) break;  // hang guard: wrong answer beats a hang
        }
      }
      __syncthreads();
    }
  }
}

// ---------------------------------------------------------------------------
__global__ void logits_kernel(const float* __restrict__ hfinal, const float* __restrict__ ow,
                              const float* __restrict__ ob, float* __restrict__ out) {
  int b = blockIdx.x / 10;
  int o = blockIdx.x % 10;
  int lane = threadIdx.x;
  const float* hrow = hfinal + b * 1024;
  const float* wrow = ow + o * 1024;
  float s = 0.f;
#pragma unroll 4
  for (int i = lane; i < 1024; i += 64) s += hrow[i] * wrow[i];
#pragma unroll
  for (int off = 32; off; off >>= 1) s += __shfl_xor(s, off);
  if (lane == 0) out[b * 10 + o] = s + ob[o];
}

// ---------------------------------------------------------------------------
extern "C" void kernel_launch(void* const* d_in, const int* in_sizes, int n_in,
                              void* d_out, int out_size, void* d_ws, size_t ws_size,
                              hipStream_t stream) {
  const float* xin = (const float*)d_in[0];
  const float* wf = (const float*)d_in[1];
  const float* bf = (const float*)d_in[2];
  const float* wi = (const float*)d_in[3];
  const float* bi = (const float*)d_in[4];
  const float* wo = (const float*)d_in[5];
  const float* bo = (const float*)d_in[6];
  const float* wc = (const float*)d_in[7];
  const float* bc = (const float*)d_in[8];
  const float* ow = (const float*)d_in[9];
  const float* ob = (const float*)d_in[10];
  (void)in_sizes; (void)n_in; (void)out_size;

  if (ws_size < WS_NEEDED) return;  // need ~47 MB scratch
  char* ws = (char*)d_ws;
  f16* x_h = (f16*)(ws + XH_OFF);
  f16x8* W_pre = (f16x8*)(ws + WPRE_OFF);
  float* bias_pre = (float*)(ws + BIAS_OFF);
  f16x8* hfrag = (f16x8*)(ws + HBUF_OFF);
  float* hfinal = (float*)(ws + HFIN_OFF);
  u32* flag = (u32*)(ws + FLG_OFF);

  const long long total = 16777216LL + 786432 + 4096 + 65536 + 32768;
  const int pblocks = (int)((total + 255) / 256);
  prep_kernel<<<pblocks, 256, 0, stream>>>(xin, wf, wi, wo, wc, bf, bi, bo, bc, x_h, W_pre,
                                           bias_pre, flag, (u32*)hfrag);
  lstm_kernel<<<NBLK, 256, 0, stream>>>(x_h, W_pre, bias_pre, hfrag, hfinal, flag);
  logits_kernel<<<640, 64, 0, stream>>>(hfinal, ow, ob, (float*)d_out);
}

// Round 4
// 4024.550 us; speedup vs baseline: 1.5648x; 1.2004x over previous
//
#include <hip/hip_runtime.h>

// CustomLSTMClassifier on MI355X (gfx950) — round 4
// Persistent 128-block kernel, 512 sequential LSTM steps.
//  - fp16 weights/activations, fp32 accum + fp32 cell state in registers.
//  - Block owns 8 hidden units (32 gate cols f/i/o/g). Weight panel prepacked
//    in MFMA-fragment order, staged to LDS once (96 KB), reused 512 steps.
//  - h exchange: block's 64x8 h tile gathered in LDS -> 64 x 16B sc1 stores
//    (write-through to L3); readers use 16B sc1 loads (L2-bypass, coherent).
//    No agent fence -> L2 stays warm for x.
//  - barrier: per-block flag words flag[t][bl]; wave0 polls with 2 coalesced
//    sc1 loads/lane + ballot.
//  - x-GEMM for step t+1 overlaps the barrier wait for step t.

typedef _Float16 f16;
typedef _Float16 f16x8 __attribute__((ext_vector_type(8)));
typedef float f32x4 __attribute__((ext_vector_type(4)));
typedef unsigned short u16;
typedef unsigned int u32;

#define NBLK 128
#define SEQ 512

// workspace layout (bytes)
#define XH_OFF 0ull
#define XH_BYTES (64ull * 512 * 512 * 2)       // 33554432  x in fp16, [t][b][k]
#define WPRE_OFF (XH_OFF + XH_BYTES)
#define WPRE_BYTES (128ull * 48 * 2 * 64 * 16) // 12582912  per-block fragment-packed W
#define BIAS_OFF (WPRE_OFF + WPRE_BYTES)
#define BIAS_BYTES (128ull * 32 * 4)
#define HBUF_OFF (BIAS_OFF + BIAS_BYTES)
#define HBUF_BYTES (2ull * 32 * 64 * 4 * 16)   // 262144: dbuf h, frag order [kt][row][lq] x f16x8
#define HFIN_OFF (HBUF_OFF + HBUF_BYTES)
#define HFIN_BYTES (64ull * 1024 * 4)          // final h (fp32)
#define FLG_OFF (HFIN_OFF + HFIN_BYTES)
#define FLG_BYTES (512ull * 128 * 4)           // 262144: flag[t][bl]
#define WS_NEEDED (FLG_OFF + FLG_BYTES)

// ---------------------------------------------------------------------------
// prep: convert x to fp16 [t][b][k]; prepack weights into per-block MFMA
// fragment order; pack bias; zero flags and h fragment-buffer 0.
// W_pre frag index = ((bl*48 + kt)*2 + nt)*64 + lane ; elem e (k-fastest).
//   col c = nt*16 + (lane&15)  (c<8:f, <16:i, <24:o, <32:g), unit = c&7
//   k    = kt*32 + 8*(lane>>4) + e   (k<512 = x part, else h part)
// ---------------------------------------------------------------------------
__global__ void prep_kernel(const float* __restrict__ xin,
                            const float* __restrict__ wf, const float* __restrict__ wi,
                            const float* __restrict__ wo, const float* __restrict__ wc,
                            const float* __restrict__ bfp, const float* __restrict__ bip,
                            const float* __restrict__ bop, const float* __restrict__ bcp,
                            f16* __restrict__ x_h, f16x8* __restrict__ W_pre,
                            float* __restrict__ bias_pre, u32* __restrict__ flagz,
                            u32* __restrict__ hzero) {
  long long id = (long long)blockIdx.x * 256 + threadIdx.x;
  const long long NX = 16777216;  // 64*512*512
  const long long NW = 786432;    // 128*48*2*64 fragments
  const long long NB_ = 4096;     // 128*32 bias
  const long long NF = 65536;     // 512*128 flags
  const long long NH = 32768;     // h frag buffer 0 as u32 words (128 KB)
  if (id < NX) {
    int b = (int)(id >> 18);
    int t = (int)((id >> 9) & 511);
    int k = (int)(id & 511);
    x_h[(((long long)t * 64 + b) << 9) | k] = (f16)xin[id];
  } else if ((id -= NX) < NW) {
    int lane = (int)(id & 63);
    int nt = (int)((id >> 6) & 1);
    int ktbl = (int)(id >> 7);
    int kt = ktbl % 48;
    int bl = ktbl / 48;
    int c = nt * 16 + (lane & 15);
    int g = c >> 3;
    int j = bl * 8 + (c & 7);
    int kbase = kt * 32 + 8 * (lane >> 4);
    const float* src = (g == 0) ? wf : (g == 1) ? wi : (g == 2) ? wo : wc;
    const float* row = src + (long long)j * 1536 + kbase;
    f16x8 v;
#pragma unroll
    for (int e = 0; e < 8; ++e) v[e] = (f16)row[e];
    W_pre[id] = v;
  } else if ((id -= NW) < NB_) {
    int bl = (int)(id >> 5);
    int c = (int)(id & 31);
    int g = c >> 3;
    int j = bl * 8 + (c & 7);
    const float* src = (g == 0) ? bfp : (g == 1) ? bip : (g == 2) ? bop : bcp;
    bias_pre[id] = src[j];
  } else if ((id -= NB_) < NF) {
    flagz[id] = 0u;
  } else if ((id -= NF) < NH) {
    hzero[id] = 0u;
  }
}

// ---------------------------------------------------------------------------
__device__ __forceinline__ float sgm(float x) { return 1.0f / (1.0f + __expf(-x)); }
__device__ __forceinline__ float tnh(float x) { return 1.0f - 2.0f / (__expf(2.0f * x) + 1.0f); }

// 16B agent-scope (sc1) load/store: L2-bypass, coherent with sc1 write-through.
__device__ __forceinline__ void ld16_sc1(f16x8* dst, const f16x8* p) {
  asm volatile("global_load_dwordx4 %0, %1, off sc1" : "=v"(*dst) : "v"(p) : "memory");
}
__device__ __forceinline__ void st16_sc1(f16x8* p, f16x8 v) {
  asm volatile("global_store_dwordx4 %0, %1, off sc1" : : "v"(p), "v"(v) : "memory");
}

// h fragment buffer layout (per 128 KB buffer):
//   f16x8 unit index = kt*256 + row*4 + lq   (kt<32, row<64, lq<4)
//   holds h[row][k] for k = kt*32 + lq*8 .. +8
__global__ __launch_bounds__(256, 1) void lstm_kernel(const f16* __restrict__ x_h,
                                                      const f16x8* __restrict__ W_pre,
                                                      const float* __restrict__ bias_pre,
                                                      f16x8* hfrag, float* hfinal, u32* flag) {
  __shared__ f16x8 Wlds[48 * 2 * 64];  // 96 KB
  __shared__ f16 hstage[64 * 8];       // 1 KB: block's h tile [row][unit]
  const int tid = threadIdx.x;
  const int bl = blockIdx.x;
  const int lane = tid & 63;
  const int wv = tid >> 6;  // 4 waves = 4 M-tiles of 16 batch rows

  {  // stage weight panel once
    const f16x8* src = W_pre + (long long)bl * (48 * 2 * 64);
    for (int i = tid; i < 48 * 2 * 64; i += 256) Wlds[i] = src[i];
  }
  __syncthreads();

  const int l15 = lane & 15;
  const int lq = lane >> 4;
  const int arow = 16 * wv + l15;           // A-fragment batch row
  const float bias0 = bias_pre[bl * 32 + l15];
  const float bias1 = bias_pre[bl * 32 + 16 + l15];
  const int jcol = bl * 8 + (lane & 7);     // owned hidden unit column
  const bool act = (l15 < 8);
  // writer address pieces (fragment layout): kt=bl>>2 const, lq-slot=bl&3 const
  const int wkt = bl >> 2;
  const int wlq = bl & 3;
  float cst0 = 0.f, cst1 = 0.f, cst2 = 0.f, cst3 = 0.f;  // fp32 cell state

  f32x4 xacc[2][2];  // [ntile][chain], x-part partial gates for next step

  auto xgemm = [&](int T) {
    f32x4 z = {0.f, 0.f, 0.f, 0.f};
    xacc[0][0] = z; xacc[0][1] = z; xacc[1][0] = z; xacc[1][1] = z;
    const f16* xr = x_h + (((long long)T * 64 + arow) << 9) + 8 * lq;
    f16x8 xf[16];
#pragma unroll
    for (int kk = 0; kk < 16; ++kk) xf[kk] = *(const f16x8*)(xr + kk * 32);
#pragma unroll
    for (int kk = 0; kk < 16; ++kk) {
      f16x8 b0 = Wlds[(kk * 2 + 0) * 64 + lane];
      f16x8 b1 = Wlds[(kk * 2 + 1) * 64 + lane];
      xacc[0][kk & 1] = __builtin_amdgcn_mfma_f32_16x16x32_f16(xf[kk], b0, xacc[0][kk & 1], 0, 0, 0);
      xacc[1][kk & 1] = __builtin_amdgcn_mfma_f32_16x16x32_f16(xf[kk], b1, xacc[1][kk & 1], 0, 0, 0);
    }
  };

  xgemm(0);  // prologue: x contribution for t=0

  for (int t = 0; t < SEQ; ++t) {
    const f16x8* hb = hfrag + (size_t)(t & 1) * 8192;     // read buffer
    f16x8* hwv_buf = hfrag + (size_t)((t + 1) & 1) * 8192;  // write buffer

    f32x4 acc00 = xacc[0][0], acc01 = xacc[0][1];
    f32x4 acc10 = xacc[1][0], acc11 = xacc[1][1];

    // ---- h-GEMM: K=1024, 32 k-tiles; 16B sc1 fragment loads ----
    const f16x8* hb0 = hb + arow * 4 + lq;
    f16x8 hfr[32];
#pragma unroll
    for (int kt = 0; kt < 32; ++kt) ld16_sc1(&hfr[kt], hb0 + kt * 256);
    asm volatile("s_waitcnt vmcnt(0)" ::: "memory");
    __builtin_amdgcn_sched_barrier(0);
#pragma unroll
    for (int kt = 0; kt < 32; ++kt) {
      f16x8 b0 = Wlds[((16 + kt) * 2 + 0) * 64 + lane];
      f16x8 b1 = Wlds[((16 + kt) * 2 + 1) * 64 + lane];
      if (kt & 1) {
        acc01 = __builtin_amdgcn_mfma_f32_16x16x32_f16(hfr[kt], b0, acc01, 0, 0, 0);
        acc11 = __builtin_amdgcn_mfma_f32_16x16x32_f16(hfr[kt], b1, acc11, 0, 0, 0);
      } else {
        acc00 = __builtin_amdgcn_mfma_f32_16x16x32_f16(hfr[kt], b0, acc00, 0, 0, 0);
        acc10 = __builtin_amdgcn_mfma_f32_16x16x32_f16(hfr[kt], b1, acc10, 0, 0, 0);
      }
    }

    // ---- gates -> elementwise.  D layout: col=lane&15, row=(lane>>4)*4+r ----
    f32x4 g0 = acc00 + acc01;  // cols 0..15: f(0-7), i(8-15)
    f32x4 g1 = acc10 + acc11;  // cols 16..31: o(0-7), g(8-15)
#pragma unroll
    for (int r = 0; r < 4; ++r) { g0[r] += bias0; g1[r] += bias1; }

    float iv0 = __shfl_xor(g0[0], 8), iv1 = __shfl_xor(g0[1], 8);
    float iv2 = __shfl_xor(g0[2], 8), iv3 = __shfl_xor(g0[3], 8);
    float gv0 = __shfl_xor(g1[0], 8), gv1 = __shfl_xor(g1[1], 8);
    float gv2 = __shfl_xor(g1[2], 8), gv3 = __shfl_xor(g1[3], 8);

    if (act) {
      const int brb = 16 * wv + 4 * lq;
#pragma unroll
      for (int r = 0; r < 4; ++r) {
        float fpre = (r == 0) ? g0[0] : (r == 1) ? g0[1] : (r == 2) ? g0[2] : g0[3];
        float opre = (r == 0) ? g1[0] : (r == 1) ? g1[1] : (r == 2) ? g1[2] : g1[3];
        float ipre = (r == 0) ? iv0 : (r == 1) ? iv1 : (r == 2) ? iv2 : iv3;
        float gpre = (r == 0) ? gv0 : (r == 1) ? gv1 : (r == 2) ? gv2 : gv3;
        float cold = (r == 0) ? cst0 : (r == 1) ? cst1 : (r == 2) ? cst2 : cst3;
        float cn = sgm(fpre) * cold + sgm(ipre) * tnh(gpre);
        float hv = sgm(opre) * tnh(cn);
        if (r == 0) cst0 = cn; else if (r == 1) cst1 = cn; else if (r == 2) cst2 = cn; else cst3 = cn;
        int row = brb + r;
        hstage[row * 8 + l15] = (f16)hv;                 // LDS gather
        if (t == SEQ - 1) hfinal[row * 1024 + jcol] = hv;
      }
    }

    // ---- gather -> 64 x 16B sc1 stores (wave 0 only) ----
    __syncthreads();  // hstage visible
    if (tid < 64) {
      f16x8 hrow = *(const f16x8*)&hstage[tid * 8];
      st16_sc1(hwv_buf + (wkt * 256 + tid * 4 + wlq), hrow);
    }

    // ---- publish + flag barrier; overlap x-GEMM(t+1) with the wait ----
    __syncthreads();  // wave0's waitcnt drains the h stores before flag
    if (t + 1 < SEQ) {
      if (tid == 0)
        __hip_atomic_store(&flag[(size_t)t * NBLK + bl], 1u, __ATOMIC_RELAXED,
                           __HIP_MEMORY_SCOPE_AGENT);
      xgemm(t + 1);
      if (wv == 0) {
        const u32* fl = flag + (size_t)t * NBLK;
        u32 it = 0;
        while (true) {
          u32 a = __hip_atomic_load(fl + 2 * lane, __ATOMIC_RELAXED, __HIP_MEMORY_SCOPE_AGENT);
          u32 b = __hip_atomic_load(fl + 2 * lane + 1, __ATOMIC_RELAXED, __HIP_MEMORY_SCOPE_AGENT);
          if (__all((a & b) == 1u)) break;  // all 128 flags set
          __builtin_amdgcn_s_sleep(1);
          if (++it > 50000u) break;  // hang guard: wrong answer beats a hang
        }
      }
      __syncthreads();
    }
  }
}

// ---------------------------------------------------------------------------
__global__ void logits_kernel(const float* __restrict__ hfinal, const float* __restrict__ ow,
                              const float* __restrict__ ob, float* __restrict__ out) {
  int b = blockIdx.x / 10;
  int o = blockIdx.x % 10;
  int lane = threadIdx.x;
  const float* hrow = hfinal + b * 1024;
  const float* wrow = ow + o * 1024;
  float s = 0.f;
#pragma unroll 4
  for (int i = lane; i < 1024; i += 64) s += hrow[i] * wrow[i];
#pragma unroll
  for (int off = 32; off; off >>= 1) s += __shfl_xor(s, off);
  if (lane == 0) out[b * 10 + o] = s + ob[o];
}

// ---------------------------------------------------------------------------
extern "C" void kernel_launch(void* const* d_in, const int* in_sizes, int n_in,
                              void* d_out, int out_size, void* d_ws, size_t ws_size,
                              hipStream_t stream) {
  const float* xin = (const float*)d_in[0];
  const float* wf = (const float*)d_in[1];
  const float* bf = (const float*)d_in[2];
  const float* wi = (const float*)d_in[3];
  const float* bi = (const float*)d_in[4];
  const float* wo = (const float*)d_in[5];
  const float* bo = (const float*)d_in[6];
  const float* wc = (const float*)d_in[7];
  const float* bc = (const float*)d_in[8];
  const float* ow = (const float*)d_in[9];
  const float* ob = (const float*)d_in[10];
  (void)in_sizes; (void)n_in; (void)out_size;

  if (ws_size < WS_NEEDED) return;  // need ~47 MB scratch
  char* ws = (char*)d_ws;
  f16* x_h = (f16*)(ws + XH_OFF);
  f16x8* W_pre = (f16x8*)(ws + WPRE_OFF);
  float* bias_pre = (float*)(ws + BIAS_OFF);
  f16x8* hfrag = (f16x8*)(ws + HBUF_OFF);
  float* hfinal = (float*)(ws + HFIN_OFF);
  u32* flag = (u32*)(ws + FLG_OFF);

  const long long total = 16777216LL + 786432 + 4096 + 65536 + 32768;
  const int pblocks = (int)((total + 255) / 256);
  prep_kernel<<<pblocks, 256, 0, stream>>>(xin, wf, wi, wo, wc, bf, bi, bo, bc, x_h, W_pre,
                                           bias_pre, flag, (u32*)hfrag);
  lstm_kernel<<<NBLK, 256, 0, stream>>>(x_h, W_pre, bias_pre, hfrag, hfinal, flag);
  logits_kernel<<<640, 64, 0, stream>>>(hfinal, ow, ob, (float*)d_out);
}